// Round 15
// baseline (712.605 us; speedup 1.0000x reference)
//
#include <hip/hip_runtime.h>
#include <hip/hip_bf16.h>

// FP4 fake-quant MLP via MX-FP4 MFMA (16x16x128, unit block scales).
// Round 15: BOTH GEMMs on the proven 256x256 4-phase pipelined structure
// (r14's g2p, now templated with RELU/FUSE_AMAX for GEMM1). Rationale: g1's
// 128^2 tile refetches Xq ~50x (FETCH 405MB for 40MB operands); the 256^2
// tile cuts the refetch ~4x and doubles MFMA per LDS byte. Elementwise and
// GEMM2 byte-identical to r14 (single-variable change).

typedef float f32x4  __attribute__((ext_vector_type(4)));
typedef int   i32x4  __attribute__((ext_vector_type(4)));
typedef int   i32x8  __attribute__((ext_vector_type(8)));

#define AS1 __attribute__((address_space(1)))
#define AS3 __attribute__((address_space(3)))

#define SB0   __builtin_amdgcn_sched_barrier(0)
#define BAR   __builtin_amdgcn_s_barrier()
#define LGKM0 asm volatile("s_waitcnt lgkmcnt(0)" ::: "memory")

// ---------- quant helpers ----------
__device__ __forceinline__ float scale_from_amax_bits(unsigned bits) {
    return fmaxf(__uint_as_float(bits) / 6.0f, 1e-12f);
}

// FP4 e2m1 code: idx 0..7 over grid {0,.5,1,1.5,2,3,4,6}, sign in bit 3.
__device__ __forceinline__ unsigned q4(float v, float inv_scale) {
    float xs = fabsf(v) * inv_scale;
    unsigned idx = 0;
    idx += (xs > 0.25f);
    idx += (xs > 0.75f);
    idx += (xs > 1.25f);
    idx += (xs > 1.75f);
    idx += (xs > 2.5f);
    idx += (xs > 3.5f);
    idx += (xs > 5.0f);
    return idx | ((v < 0.0f) ? 8u : 0u);
}

// ---------- tiny utility kernels ----------
__global__ void zero4_kernel(unsigned* p) {
    if (threadIdx.x < 4) p[threadIdx.x] = 0u;
}

__global__ void sentinel_kernel(float* out, long long n) {
    long long i = (long long)blockIdx.x * blockDim.x + threadIdx.x;
    long long stride = (long long)gridDim.x * blockDim.x;
    for (; i < n; i += stride) out[i] = 1e30f;
}

// ---------- absmax reduction (n % 4 == 0) ----------
__global__ void absmax_kernel(const float* __restrict__ in, long long n,
                              unsigned* __restrict__ out) {
    long long i = ((long long)blockIdx.x * blockDim.x + threadIdx.x) * 4;
    long long stride = (long long)gridDim.x * blockDim.x * 4;
    float m = 0.0f;
    for (; i < n; i += stride) {
        f32x4 v = *(const f32x4*)&in[i];
        m = fmaxf(m, fmaxf(fmaxf(fabsf(v.x), fabsf(v.y)),
                           fmaxf(fabsf(v.z), fabsf(v.w))));
    }
    #pragma unroll
    for (int off = 32; off > 0; off >>= 1)
        m = fmaxf(m, __shfl_xor(m, off));
    __shared__ float smax[4];
    int lane = threadIdx.x & 63, w = threadIdx.x >> 6;
    if (lane == 0) smax[w] = m;
    __syncthreads();
    if (threadIdx.x == 0) {
        m = fmaxf(fmaxf(smax[0], smax[1]), fmaxf(smax[2], smax[3]));
        atomicMax(out, __float_as_uint(m));  // valid: all values >= 0
    }
}

// ---------- quantize f32 -> packed fp4, reversed, NT loads (last use) -------
__global__ void quant_pack_rev_kernel(const float* __restrict__ in, long long n,
                                      const unsigned* __restrict__ amax,
                                      unsigned* __restrict__ out) {
    float inv = 1.0f / scale_from_amax_bits(*amax);
    long long nw = n >> 3;
    long long gid = (long long)blockIdx.x * blockDim.x + threadIdx.x;
    long long gs = (long long)gridDim.x * blockDim.x;
    for (long long j = nw - 1 - gid; j >= 0; j -= gs) {
        long long i = j * 8;
        f32x4 a = __builtin_nontemporal_load((const f32x4*)&in[i]);
        f32x4 b = __builtin_nontemporal_load((const f32x4*)&in[i + 4]);
        unsigned u = q4(a.x, inv)        | (q4(a.y, inv) << 4)
                   | (q4(a.z, inv) << 8) | (q4(a.w, inv) << 12)
                   | (q4(b.x, inv) << 16)| (q4(b.y, inv) << 20)
                   | (q4(b.z, inv) << 24)| (q4(b.w, inv) << 28);
        out[j] = u;
    }
}

// ---------- quantize + transpose + pack, reversed tiles, NT loads ----------
__global__ void quant_transpose_pack_kernel(const float* __restrict__ in, int R, int C,
                                            const unsigned* __restrict__ amax,
                                            unsigned char* __restrict__ out) {
    __shared__ float tile[64][65];
    float inv = 1.0f / scale_from_amax_bits(*amax);
    int t = threadIdx.x;
    int bid = gridDim.x - 1 - blockIdx.x;   // reverse: L3-resident tail first
    int CT = C >> 6;
    int tc = bid % CT;
    int tr = bid / CT;
    int r0 = t >> 4;
    int c0 = (t & 15) * 4;
    #pragma unroll
    for (int it = 0; it < 4; ++it) {
        int r = r0 + it * 16;
        f32x4 v = __builtin_nontemporal_load(
            (const f32x4*)&in[(size_t)(tr * 64 + r) * C + tc * 64 + c0]);
        tile[r][c0 + 0] = v.x;
        tile[r][c0 + 1] = v.y;
        tile[r][c0 + 2] = v.z;
        tile[r][c0 + 3] = v.w;
    }
    __syncthreads();
    int c = t >> 2;
    int rch = (t & 3) * 16;
    unsigned u0 = 0, u1 = 0;
    #pragma unroll
    for (int j = 0; j < 8; ++j) u0 |= q4(tile[rch + j][c], inv) << (4 * j);
    #pragma unroll
    for (int j = 0; j < 8; ++j) u1 |= q4(tile[rch + 8 + j][c], inv) << (4 * j);
    uint2 o; o.x = u0; o.y = u1;
    *(uint2*)&out[(size_t)(tc * 64 + c) * (R >> 1) + (size_t)(tr * 32) + (rch >> 1)] = o;
}

// ---------- fp4 MFMA helper ----------
__device__ __forceinline__ f32x4 mm16(i32x4 a, i32x4 b, f32x4 c) {
    i32x8 a8 = {a[0], a[1], a[2], a[3], 0, 0, 0, 0};
    i32x8 b8 = {b[0], b[1], b[2], b[3], 0, 0, 0, 0};
    return __builtin_amdgcn_mfma_scale_f32_16x16x128_f8f6f4(
        a8, b8, c, 4, 4, 0, 0x7f7f7f7f, 0, 0x7f7f7f7f);
}

// ====== 256x256 block, BK=128, 4-phase pipelined, 512 thr, 64KB LDS =========
// 8 waves (2M x 4N), wave tile 128x64: a[8] x b[4] = 32 MFMA / K-tile.
// 2-tile-deep prefetch, counted vmcnt(4); stage targets only slots whose
// reads retired >=1 barrier earlier (verified r14, refcheck'd absmax 2.0).
template <int RELU, int FUSE_AMAX>
__global__ __launch_bounds__(512, 2)
void gemm_fp4_p(const unsigned char* __restrict__ Ap,
                const unsigned char* __restrict__ Bp,
                float* __restrict__ C, const float* __restrict__ bias,
                const unsigned* __restrict__ amaxA,
                const unsigned* __restrict__ amaxB,
                unsigned* __restrict__ amaxOut,
                int M, int N, int K) {
    __shared__ alignas(16) unsigned char As[2][256 * 64];  // 32 KB
    __shared__ alignas(16) unsigned char Bs[2][256 * 64];  // 32 KB
    __shared__ float smax[8];

    int nwg = gridDim.x, cpx = nwg >> 3;
    int wg = (blockIdx.x & 7) * cpx + (blockIdx.x >> 3);
    int MT = M >> 8;
    int tm = wg % MT, tn = wg / MT;

    int tid = threadIdx.x, lane = tid & 63, wid = tid >> 6;  // wid 0..7
    int wr = wid >> 2;          // 0..1 : 128-row half
    int wc = wid & 3;           // 0..3 : 64-col quarter

    size_t Kb = (size_t)(K >> 1);

    // staging: thread tid covers row tid>>2 (0..127), chunk tid&3; source
    // chunk pre-swizzled with the r8 involution slot = chunk ^ ((row>>1)&3).
    int csw = ((tid & 3) ^ ((tid >> 3) & 3)) << 4;
    int srow = tid >> 2;
    const unsigned char* Abase = Ap + (size_t)(tm * 256 + srow) * Kb + csw;
    const unsigned char* Bbase = Bp + (size_t)(tn * 256 + srow) * Kb + csw;
    char* AsB = (char*)As;
    char* BsB = (char*)Bs;
    int dstOff = wid << 10;     // + lane*16 by HW

#define STG_A2(d, kt, h)                                                      \
    __builtin_amdgcn_global_load_lds(                                         \
        (const AS1 void*)(Abase + (size_t)(kt) * 64 + (size_t)((h) * 128) * Kb), \
        (AS3 void*)(AsB + ((d) << 14) + ((h) << 13) + dstOff), 16, 0, 0)
#define STG_B2(d, kt, h)                                                      \
    __builtin_amdgcn_global_load_lds(                                         \
        (const AS1 void*)(Bbase + (size_t)(kt) * 64 + (size_t)((h) * 128) * Kb), \
        (AS3 void*)(BsB + ((d) << 14) + ((h) << 13) + dstOff), 16, 0, 0)

    f32x4 acc[8][4] = {};
    int l15 = lane & 15;
    int rrA = wr * 128 + l15;   // + mi*16
    int rrB = wc * 64 + l15;    // + ni*16
    int slotOff = (((lane >> 4) ^ ((lane >> 1) & 3)) << 4);

    int KT = K >> 7;            // K-tiles of 128 fp4 (64B)

    // prologue: tile 0 -> buf0, tile 1 -> buf1; retire tile 0 (leave 4)
    STG_A2(0, 0, 0); STG_A2(0, 0, 1); STG_B2(0, 0, 0); STG_B2(0, 0, 1);
    STG_A2(1, 1, 0); STG_A2(1, 1, 1); STG_B2(1, 1, 0); STG_B2(1, 1, 1);
    asm volatile("s_waitcnt vmcnt(4)" ::: "memory");
    BAR;

    for (int t = 0; t < KT; ++t) {
        int d = t & 1;
        const char* Aq = AsB + (d << 14);
        const char* Bq = BsB + (d << 14);
        bool pf = (t + 2 < KT);
        i32x4 a0[4], a1[4], b[4];

        // ---- P1: read a[0..3] + b[0..3]; MFMA a0 x b01
        #pragma unroll
        for (int mi = 0; mi < 4; ++mi)
            a0[mi] = *(const i32x4*)(Aq + (rrA + mi * 16) * 64 + slotOff);
        #pragma unroll
        for (int ni = 0; ni < 4; ++ni)
            b[ni] = *(const i32x4*)(Bq + (rrB + ni * 16) * 64 + slotOff);
        SB0; BAR;
        LGKM0; SB0;
        __builtin_amdgcn_s_setprio(1);
        #pragma unroll
        for (int mi = 0; mi < 4; ++mi)
            #pragma unroll
            for (int ni = 0; ni < 2; ++ni)
                acc[mi][ni] = mm16(a0[mi], b[ni], acc[mi][ni]);
        __builtin_amdgcn_s_setprio(0);
        SB0; BAR;

        // ---- P2: read a[4..7]; stage B(t+2) into buf d (B reads retired P1)
        #pragma unroll
        for (int mi = 0; mi < 4; ++mi)
            a1[mi] = *(const i32x4*)(Aq + (rrA + (4 + mi) * 16) * 64 + slotOff);
        if (pf) { STG_B2(d, t + 2, 0); STG_B2(d, t + 2, 1); }
        SB0; BAR;
        __builtin_amdgcn_s_setprio(1);
        #pragma unroll
        for (int mi = 0; mi < 4; ++mi)
            #pragma unroll
            for (int ni = 2; ni < 4; ++ni)
                acc[mi][ni] = mm16(a0[mi], b[ni], acc[mi][ni]);
        __builtin_amdgcn_s_setprio(0);
        SB0;
        LGKM0;              // a1 retired before P2-end barrier
        BAR;

        // ---- P3: stage A(t+2) into buf d (A reads retired above); MFMA
        if (pf) { STG_A2(d, t + 2, 0); STG_A2(d, t + 2, 1); }
        SB0; BAR;
        __builtin_amdgcn_s_setprio(1);
        #pragma unroll
        for (int mi = 0; mi < 4; ++mi)
            #pragma unroll
            for (int ni = 0; ni < 2; ++ni)
                acc[4 + mi][ni] = mm16(a1[mi], b[ni], acc[4 + mi][ni]);
        __builtin_amdgcn_s_setprio(0);
        SB0; BAR;

        // ---- P4: MFMA; counted vmcnt gate (retire tile t+1's 4 loads)
        __builtin_amdgcn_s_setprio(1);
        #pragma unroll
        for (int mi = 0; mi < 4; ++mi)
            #pragma unroll
            for (int ni = 2; ni < 4; ++ni)
                acc[4 + mi][ni] = mm16(a1[mi], b[ni], acc[4 + mi][ni]);
        __builtin_amdgcn_s_setprio(0);
        SB0;
        if (pf) { asm volatile("s_waitcnt vmcnt(4)" ::: "memory"); }
        else    { asm volatile("s_waitcnt vmcnt(0)" ::: "memory"); }
        BAR;
    }
#undef STG_A2
#undef STG_B2

    float s = scale_from_amax_bits(*amaxA) * scale_from_amax_bits(*amaxB);
    float vmax = 0.0f;
    int rowBase = tm * 256 + wr * 128 + (lane >> 4) * 4;
    int colBase = tn * 256 + wc * 64 + l15;
    #pragma unroll
    for (int mi = 0; mi < 8; ++mi) {
        #pragma unroll
        for (int ni = 0; ni < 4; ++ni) {
            int col = colBase + ni * 16;
            float bv = bias[col];
            int row = rowBase + mi * 16;
            #pragma unroll
            for (int r = 0; r < 4; ++r) {
                float v = acc[mi][ni][r] * s + bv;
                if (RELU) v = fmaxf(v, 0.0f);
                if (FUSE_AMAX) vmax = fmaxf(vmax, fabsf(v));
                __builtin_nontemporal_store(v, &C[(size_t)(row + r) * N + col]);
            }
        }
    }
    if (FUSE_AMAX) {
        #pragma unroll
        for (int off = 32; off > 0; off >>= 1)
            vmax = fmaxf(vmax, __shfl_xor(vmax, off));
        if (lane == 0) smax[wid] = vmax;
        __syncthreads();
        if (tid == 0) {
            float m = smax[0];
            #pragma unroll
            for (int i = 1; i < 8; ++i) m = fmaxf(m, smax[i]);
            atomicMax(amaxOut, __float_as_uint(m));
        }
    }
}

// ---------- launch ----------
extern "C" void kernel_launch(void* const* d_in, const int* in_sizes, int n_in,
                              void* d_out, int out_size, void* d_ws, size_t ws_size,
                              hipStream_t stream) {
    const float* x  = (const float*)d_in[0];
    const float* w1 = (const float*)d_in[1];
    const float* b1 = (const float*)d_in[2];
    const float* w2 = (const float*)d_in[3];
    const float* b2 = (const float*)d_in[4];
    float* out = (float*)d_out;

    const int B = 4096, DIN = 4096, DH = 16384, DOUT = 4096;

    const size_t off_amax = 0;                                    // 4 uints
    const size_t off_Xq   = 256;                                  // 8 MB
    const size_t off_W    = off_Xq + (size_t)B * DIN / 2;         // 32 MB
    const size_t off_h    = off_W + (size_t)DIN * DH / 2;         // 256 MB f32
    const size_t off_Hq   = off_h + (size_t)B * DH * 4;           // 32 MB
    const size_t needed   = off_Hq + (size_t)B * DH / 2;

    if (ws_size < needed) {
        sentinel_kernel<<<2048, 256, 0, stream>>>(out, (long long)out_size);
        return;
    }

    char* ws = (char*)d_ws;
    unsigned* amax = (unsigned*)(ws + off_amax);  // [0]=x [1]=w1 [2]=h [3]=w2
    unsigned char* Xq = (unsigned char*)(ws + off_Xq);
    unsigned char* Wq = (unsigned char*)(ws + off_W);
    float*         h  = (float*)(ws + off_h);
    unsigned char* Hq = (unsigned char*)(ws + off_Hq);

    zero4_kernel<<<1, 64, 0, stream>>>(amax);

    // --- w1: absmax then immediate reversed re-read (L3-adjacent) ---
    absmax_kernel<<<2048, 256, 0, stream>>>(w1, (long long)DIN * DH, amax + 1);
    quant_transpose_pack_kernel<<<(DIN / 64) * (DH / 64), 256, 0, stream>>>(
        w1, DIN, DH, amax + 1, Wq);

    // --- x: absmax then immediate quant ---
    absmax_kernel<<<2048, 256, 0, stream>>>(x, (long long)B * DIN, amax + 0);
    quant_pack_rev_kernel<<<2048, 256, 0, stream>>>(x, (long long)B * DIN,
                                                    amax + 0, (unsigned*)Xq);

    // h = relu(Q(x) @ Q(w1) + b1), fused absmax(h) -> amax[2]  [256^2 pipeline]
    gemm_fp4_p<1, 1><<<(B / 256) * (DH / 256), 512, 0, stream>>>(
        Xq, Wq, h, b1, amax + 0, amax + 1, amax + 2, B, DH, DIN);

    // --- h: quant immediately after GEMM1, reversed, NT loads ---
    quant_pack_rev_kernel<<<2048, 256, 0, stream>>>(h, (long long)B * DH,
                                                    amax + 2, (unsigned*)Hq);

    // --- w2: absmax then immediate reversed re-read ---
    absmax_kernel<<<2048, 256, 0, stream>>>(w2, (long long)DH * DOUT, amax + 3);
    quant_transpose_pack_kernel<<<(DH / 64) * (DOUT / 64), 256, 0, stream>>>(
        w2, DH, DOUT, amax + 3, Wq);

    // out = Q(h) @ Q(w2) + b2   [256^2 pipeline]
    gemm_fp4_p<0, 0><<<(B / 256) * (DOUT / 256), 512, 0, stream>>>(
        Hq, Wq, out, b2, amax + 2, amax + 3, nullptr, B, DOUT, DH);
}

// Round 16
// 676.408 us; speedup vs baseline: 1.0535x; 1.0535x over previous
//
#include <hip/hip_runtime.h>
#include <hip/hip_bf16.h>

// FP4 fake-quant MLP via MX-FP4 MFMA (16x16x128, unit block scales).
// Round 16: revert GEMM1 to r13-g1 (256^2 pipeline lost: 253 vs 197 -- tile
// cut FETCH 405->147MB but schedule efficiency dropped). Single change vs r14:
// g1's block->tile map is now tn-FAST. Per XCD the ~64 concurrent blocks then
// span 1 tm x 64 tn: A-panel (256KB) L2-resident, Wq tn-panels swept in the
// same order by all XCDs (L3-resident) -> Xq refetch (~400MB) should vanish.
// GEMM2 = r14 g2p (162us, proven). Elementwise byte-identical to r14.

typedef float f32x4  __attribute__((ext_vector_type(4)));
typedef int   i32x4  __attribute__((ext_vector_type(4)));
typedef int   i32x8  __attribute__((ext_vector_type(8)));

#define AS1 __attribute__((address_space(1)))
#define AS3 __attribute__((address_space(3)))

#define SB0   __builtin_amdgcn_sched_barrier(0)
#define BAR   __builtin_amdgcn_s_barrier()
#define LGKM0 asm volatile("s_waitcnt lgkmcnt(0)" ::: "memory")

// ---------- quant helpers ----------
__device__ __forceinline__ float scale_from_amax_bits(unsigned bits) {
    return fmaxf(__uint_as_float(bits) / 6.0f, 1e-12f);
}

// FP4 e2m1 code: idx 0..7 over grid {0,.5,1,1.5,2,3,4,6}, sign in bit 3.
__device__ __forceinline__ unsigned q4(float v, float inv_scale) {
    float xs = fabsf(v) * inv_scale;
    unsigned idx = 0;
    idx += (xs > 0.25f);
    idx += (xs > 0.75f);
    idx += (xs > 1.25f);
    idx += (xs > 1.75f);
    idx += (xs > 2.5f);
    idx += (xs > 3.5f);
    idx += (xs > 5.0f);
    return idx | ((v < 0.0f) ? 8u : 0u);
}

// ---------- tiny utility kernels ----------
__global__ void zero4_kernel(unsigned* p) {
    if (threadIdx.x < 4) p[threadIdx.x] = 0u;
}

__global__ void sentinel_kernel(float* out, long long n) {
    long long i = (long long)blockIdx.x * blockDim.x + threadIdx.x;
    long long stride = (long long)gridDim.x * blockDim.x;
    for (; i < n; i += stride) out[i] = 1e30f;
}

// ---------- absmax reduction (n % 4 == 0) ----------
__global__ void absmax_kernel(const float* __restrict__ in, long long n,
                              unsigned* __restrict__ out) {
    long long i = ((long long)blockIdx.x * blockDim.x + threadIdx.x) * 4;
    long long stride = (long long)gridDim.x * blockDim.x * 4;
    float m = 0.0f;
    for (; i < n; i += stride) {
        f32x4 v = *(const f32x4*)&in[i];
        m = fmaxf(m, fmaxf(fmaxf(fabsf(v.x), fabsf(v.y)),
                           fmaxf(fabsf(v.z), fabsf(v.w))));
    }
    #pragma unroll
    for (int off = 32; off > 0; off >>= 1)
        m = fmaxf(m, __shfl_xor(m, off));
    __shared__ float smax[4];
    int lane = threadIdx.x & 63, w = threadIdx.x >> 6;
    if (lane == 0) smax[w] = m;
    __syncthreads();
    if (threadIdx.x == 0) {
        m = fmaxf(fmaxf(smax[0], smax[1]), fmaxf(smax[2], smax[3]));
        atomicMax(out, __float_as_uint(m));  // valid: all values >= 0
    }
}

// ---------- quantize f32 -> packed fp4, reversed, NT loads (last use) -------
__global__ void quant_pack_rev_kernel(const float* __restrict__ in, long long n,
                                      const unsigned* __restrict__ amax,
                                      unsigned* __restrict__ out) {
    float inv = 1.0f / scale_from_amax_bits(*amax);
    long long nw = n >> 3;
    long long gid = (long long)blockIdx.x * blockDim.x + threadIdx.x;
    long long gs = (long long)gridDim.x * blockDim.x;
    for (long long j = nw - 1 - gid; j >= 0; j -= gs) {
        long long i = j * 8;
        f32x4 a = __builtin_nontemporal_load((const f32x4*)&in[i]);
        f32x4 b = __builtin_nontemporal_load((const f32x4*)&in[i + 4]);
        unsigned u = q4(a.x, inv)        | (q4(a.y, inv) << 4)
                   | (q4(a.z, inv) << 8) | (q4(a.w, inv) << 12)
                   | (q4(b.x, inv) << 16)| (q4(b.y, inv) << 20)
                   | (q4(b.z, inv) << 24)| (q4(b.w, inv) << 28);
        out[j] = u;
    }
}

// ---------- quantize + transpose + pack, reversed tiles, NT loads ----------
__global__ void quant_transpose_pack_kernel(const float* __restrict__ in, int R, int C,
                                            const unsigned* __restrict__ amax,
                                            unsigned char* __restrict__ out) {
    __shared__ float tile[64][65];
    float inv = 1.0f / scale_from_amax_bits(*amax);
    int t = threadIdx.x;
    int bid = gridDim.x - 1 - blockIdx.x;   // reverse: L3-resident tail first
    int CT = C >> 6;
    int tc = bid % CT;
    int tr = bid / CT;
    int r0 = t >> 4;
    int c0 = (t & 15) * 4;
    #pragma unroll
    for (int it = 0; it < 4; ++it) {
        int r = r0 + it * 16;
        f32x4 v = __builtin_nontemporal_load(
            (const f32x4*)&in[(size_t)(tr * 64 + r) * C + tc * 64 + c0]);
        tile[r][c0 + 0] = v.x;
        tile[r][c0 + 1] = v.y;
        tile[r][c0 + 2] = v.z;
        tile[r][c0 + 3] = v.w;
    }
    __syncthreads();
    int c = t >> 2;
    int rch = (t & 3) * 16;
    unsigned u0 = 0, u1 = 0;
    #pragma unroll
    for (int j = 0; j < 8; ++j) u0 |= q4(tile[rch + j][c], inv) << (4 * j);
    #pragma unroll
    for (int j = 0; j < 8; ++j) u1 |= q4(tile[rch + 8 + j][c], inv) << (4 * j);
    uint2 o; o.x = u0; o.y = u1;
    *(uint2*)&out[(size_t)(tc * 64 + c) * (R >> 1) + (size_t)(tr * 32) + (rch >> 1)] = o;
}

// ---------- fp4 MFMA helper ----------
__device__ __forceinline__ f32x4 mm16(i32x4 a, i32x4 b, f32x4 c) {
    i32x8 a8 = {a[0], a[1], a[2], a[3], 0, 0, 0, 0};
    i32x8 b8 = {b[0], b[1], b[2], b[3], 0, 0, 0, 0};
    return __builtin_amdgcn_mfma_scale_f32_16x16x128_f8f6f4(
        a8, b8, c, 4, 4, 0, 0x7f7f7f7f, 0, 0x7f7f7f7f);
}

// ====== g1: r13 structure — 128x128 block, BK=256, single-buffer =============
// ONLY change vs r13/r14: tn-FAST tile mapping (tn = wg % NT) so each XCD's
// concurrent blocks share one A-panel (L2) and sweep B-panels in lockstep (L3).
template <int RELU, int FUSE_AMAX>
__global__ __launch_bounds__(256, 2)
void gemm_fp4_g1(const unsigned char* __restrict__ Ap,
                 const unsigned char* __restrict__ Bp,
                 float* __restrict__ C, const float* __restrict__ bias,
                 const unsigned* __restrict__ amaxA,
                 const unsigned* __restrict__ amaxB,
                 unsigned* __restrict__ amaxOut,
                 int M, int N, int K) {
    __shared__ alignas(16) unsigned char As[128 * 128];
    __shared__ alignas(16) unsigned char Bs[128 * 128];
    __shared__ float smax[4];

    int nwg = gridDim.x, cpx = nwg >> 3;
    int wg = (blockIdx.x & 7) * cpx + (blockIdx.x >> 3);
    int NTl = N >> 7;
    int tn = wg % NTl, tm = wg / NTl;   // tn-fast (was tm-fast)

    int tid = threadIdx.x, lane = tid & 63, wid = tid >> 6;
    int wr = wid >> 1, wc = wid & 1;

    size_t Kb = (size_t)(K >> 1);

    int cs = ((lane & 7) ^ ((lane >> 3) & 7)) << 4;
    int srow = wid * 32 + (lane >> 3);
    const unsigned char* Abase = Ap + (size_t)(tm * 128 + srow) * Kb + cs;
    const unsigned char* Bbase = Bp + (size_t)(tn * 128 + srow) * Kb + cs;
    char* AsB = (char*)As;
    char* BsB = (char*)Bs;
    int ldsOff = wid * 4096;

    f32x4 acc[4][4] = {};
    int rrA = wr * 64 + (lane & 15);
    int rrB = wc * 64 + (lane & 15);

    int KT = K >> 8;
    for (int kt = 0; kt < KT; ++kt) {
        #pragma unroll
        for (int i = 0; i < 4; ++i) {
            __builtin_amdgcn_global_load_lds(
                (const AS1 void*)(Abase + (size_t)kt * 128 + (size_t)(i * 8) * Kb),
                (AS3 void*)(AsB + ldsOff + i * 1024), 16, 0, 0);
            __builtin_amdgcn_global_load_lds(
                (const AS1 void*)(Bbase + (size_t)kt * 128 + (size_t)(i * 8) * Kb),
                (AS3 void*)(BsB + ldsOff + i * 1024), 16, 0, 0);
        }
        __syncthreads();

        #pragma unroll
        for (int ks = 0; ks < 2; ++ks) {
            int slotOff = ((ks * 4 + (lane >> 4)) ^ (lane & 7)) << 4;
            i32x4 a[4], b[4];
            #pragma unroll
            for (int mi = 0; mi < 4; ++mi)
                a[mi] = *(const i32x4*)(AsB + (rrA + mi * 16) * 128 + slotOff);
            #pragma unroll
            for (int ni = 0; ni < 4; ++ni)
                b[ni] = *(const i32x4*)(BsB + (rrB + ni * 16) * 128 + slotOff);
            #pragma unroll
            for (int mi = 0; mi < 4; ++mi)
                #pragma unroll
                for (int ni = 0; ni < 4; ++ni)
                    acc[mi][ni] = mm16(a[mi], b[ni], acc[mi][ni]);
        }
        __syncthreads();
    }

    float s = scale_from_amax_bits(*amaxA) * scale_from_amax_bits(*amaxB);
    float vmax = 0.0f;
    int rowBase = tm * 128 + wr * 64 + (lane >> 4) * 4;
    int colBase = tn * 128 + wc * 64 + (lane & 15);
    #pragma unroll
    for (int mi = 0; mi < 4; ++mi) {
        #pragma unroll
        for (int ni = 0; ni < 4; ++ni) {
            int col = colBase + ni * 16;
            float bv = bias[col];
            int row = rowBase + mi * 16;
            #pragma unroll
            for (int r = 0; r < 4; ++r) {
                float v = acc[mi][ni][r] * s + bv;
                if (RELU) v = fmaxf(v, 0.0f);
                if (FUSE_AMAX) vmax = fmaxf(vmax, fabsf(v));
                __builtin_nontemporal_store(v, &C[(size_t)(row + r) * N + col]);
            }
        }
    }
    if (FUSE_AMAX) {
        #pragma unroll
        for (int off = 32; off > 0; off >>= 1)
            vmax = fmaxf(vmax, __shfl_xor(vmax, off));
        if (lane == 0) smax[wid] = vmax;
        __syncthreads();
        if (tid == 0) {
            vmax = fmaxf(fmaxf(smax[0], smax[1]), fmaxf(smax[2], smax[3]));
            atomicMax(amaxOut, __float_as_uint(vmax));
        }
    }
}

// ====== g2: 256x256 block, BK=128, 4-phase pipelined (r14 g2p, proven) ======
__global__ __launch_bounds__(512, 2)
void gemm_fp4_g2p(const unsigned char* __restrict__ Ap,
                  const unsigned char* __restrict__ Bp,
                  float* __restrict__ C, const float* __restrict__ bias,
                  const unsigned* __restrict__ amaxA,
                  const unsigned* __restrict__ amaxB,
                  int M, int N, int K) {
    __shared__ alignas(16) unsigned char As[2][256 * 64];  // 32 KB
    __shared__ alignas(16) unsigned char Bs[2][256 * 64];  // 32 KB

    int nwg = gridDim.x, cpx = nwg >> 3;
    int wg = (blockIdx.x & 7) * cpx + (blockIdx.x >> 3);
    int MT = M >> 8;
    int tm = wg % MT, tn = wg / MT;

    int tid = threadIdx.x, lane = tid & 63, wid = tid >> 6;  // wid 0..7
    int wr = wid >> 2;          // 0..1 : 128-row half
    int wc = wid & 3;           // 0..3 : 64-col quarter

    size_t Kb = (size_t)(K >> 1);

    int csw = ((tid & 3) ^ ((tid >> 3) & 3)) << 4;
    int srow = tid >> 2;
    const unsigned char* Abase = Ap + (size_t)(tm * 256 + srow) * Kb + csw;
    const unsigned char* Bbase = Bp + (size_t)(tn * 256 + srow) * Kb + csw;
    char* AsB = (char*)As;
    char* BsB = (char*)Bs;
    int dstOff = wid << 10;     // + lane*16 by HW

#define STG_A2(d, kt, h)                                                      \
    __builtin_amdgcn_global_load_lds(                                         \
        (const AS1 void*)(Abase + (size_t)(kt) * 64 + (size_t)((h) * 128) * Kb), \
        (AS3 void*)(AsB + ((d) << 14) + ((h) << 13) + dstOff), 16, 0, 0)
#define STG_B2(d, kt, h)                                                      \
    __builtin_amdgcn_global_load_lds(                                         \
        (const AS1 void*)(Bbase + (size_t)(kt) * 64 + (size_t)((h) * 128) * Kb), \
        (AS3 void*)(BsB + ((d) << 14) + ((h) << 13) + dstOff), 16, 0, 0)

    f32x4 acc[8][4] = {};
    int l15 = lane & 15;
    int rrA = wr * 128 + l15;   // + mi*16
    int rrB = wc * 64 + l15;    // + ni*16
    int slotOff = (((lane >> 4) ^ ((lane >> 1) & 3)) << 4);

    int KT = K >> 7;            // K-tiles of 128 fp4 (64B)

    // prologue: tile 0 -> buf0, tile 1 -> buf1; retire tile 0 (leave 4)
    STG_A2(0, 0, 0); STG_A2(0, 0, 1); STG_B2(0, 0, 0); STG_B2(0, 0, 1);
    STG_A2(1, 1, 0); STG_A2(1, 1, 1); STG_B2(1, 1, 0); STG_B2(1, 1, 1);
    asm volatile("s_waitcnt vmcnt(4)" ::: "memory");
    BAR;

    for (int t = 0; t < KT; ++t) {
        int d = t & 1;
        const char* Aq = AsB + (d << 14);
        const char* Bq = BsB + (d << 14);
        bool pf = (t + 2 < KT);
        i32x4 a0[4], a1[4], b[4];

        // ---- P1: read a[0..3] + b[0..3]; MFMA a0 x b01
        #pragma unroll
        for (int mi = 0; mi < 4; ++mi)
            a0[mi] = *(const i32x4*)(Aq + (rrA + mi * 16) * 64 + slotOff);
        #pragma unroll
        for (int ni = 0; ni < 4; ++ni)
            b[ni] = *(const i32x4*)(Bq + (rrB + ni * 16) * 64 + slotOff);
        SB0; BAR;
        LGKM0; SB0;
        __builtin_amdgcn_s_setprio(1);
        #pragma unroll
        for (int mi = 0; mi < 4; ++mi)
            #pragma unroll
            for (int ni = 0; ni < 2; ++ni)
                acc[mi][ni] = mm16(a0[mi], b[ni], acc[mi][ni]);
        __builtin_amdgcn_s_setprio(0);
        SB0; BAR;

        // ---- P2: read a[4..7]; stage B(t+2) into buf d (B reads retired P1)
        #pragma unroll
        for (int mi = 0; mi < 4; ++mi)
            a1[mi] = *(const i32x4*)(Aq + (rrA + (4 + mi) * 16) * 64 + slotOff);
        if (pf) { STG_B2(d, t + 2, 0); STG_B2(d, t + 2, 1); }
        SB0; BAR;
        __builtin_amdgcn_s_setprio(1);
        #pragma unroll
        for (int mi = 0; mi < 4; ++mi)
            #pragma unroll
            for (int ni = 2; ni < 4; ++ni)
                acc[mi][ni] = mm16(a0[mi], b[ni], acc[mi][ni]);
        __builtin_amdgcn_s_setprio(0);
        SB0;
        LGKM0;              // a1 retired before P2-end barrier
        BAR;

        // ---- P3: stage A(t+2) into buf d (A reads retired above); MFMA
        if (pf) { STG_A2(d, t + 2, 0); STG_A2(d, t + 2, 1); }
        SB0; BAR;
        __builtin_amdgcn_s_setprio(1);
        #pragma unroll
        for (int mi = 0; mi < 4; ++mi)
            #pragma unroll
            for (int ni = 0; ni < 2; ++ni)
                acc[4 + mi][ni] = mm16(a1[mi], b[ni], acc[4 + mi][ni]);
        __builtin_amdgcn_s_setprio(0);
        SB0; BAR;

        // ---- P4: MFMA; counted vmcnt gate (retire tile t+1's 4 loads)
        __builtin_amdgcn_s_setprio(1);
        #pragma unroll
        for (int mi = 0; mi < 4; ++mi)
            #pragma unroll
            for (int ni = 2; ni < 4; ++ni)
                acc[4 + mi][ni] = mm16(a1[mi], b[ni], acc[4 + mi][ni]);
        __builtin_amdgcn_s_setprio(0);
        SB0;
        if (pf) { asm volatile("s_waitcnt vmcnt(4)" ::: "memory"); }
        else    { asm volatile("s_waitcnt vmcnt(0)" ::: "memory"); }
        BAR;
    }
#undef STG_A2
#undef STG_B2

    float s = scale_from_amax_bits(*amaxA) * scale_from_amax_bits(*amaxB);
    int rowBase = tm * 256 + wr * 128 + (lane >> 4) * 4;
    int colBase = tn * 256 + wc * 64 + l15;
    #pragma unroll
    for (int mi = 0; mi < 8; ++mi) {
        #pragma unroll
        for (int ni = 0; ni < 4; ++ni) {
            int col = colBase + ni * 16;
            float bv = bias[col];
            int row = rowBase + mi * 16;
            #pragma unroll
            for (int r = 0; r < 4; ++r) {
                float v = acc[mi][ni][r] * s + bv;
                __builtin_nontemporal_store(v, &C[(size_t)(row + r) * N + col]);
            }
        }
    }
}

// ---------- launch ----------
extern "C" void kernel_launch(void* const* d_in, const int* in_sizes, int n_in,
                              void* d_out, int out_size, void* d_ws, size_t ws_size,
                              hipStream_t stream) {
    const float* x  = (const float*)d_in[0];
    const float* w1 = (const float*)d_in[1];
    const float* b1 = (const float*)d_in[2];
    const float* w2 = (const float*)d_in[3];
    const float* b2 = (const float*)d_in[4];
    float* out = (float*)d_out;

    const int B = 4096, DIN = 4096, DH = 16384, DOUT = 4096;

    const size_t off_amax = 0;                                    // 4 uints
    const size_t off_Xq   = 256;                                  // 8 MB
    const size_t off_W    = off_Xq + (size_t)B * DIN / 2;         // 32 MB
    const size_t off_h    = off_W + (size_t)DIN * DH / 2;         // 256 MB f32
    const size_t off_Hq   = off_h + (size_t)B * DH * 4;           // 32 MB
    const size_t needed   = off_Hq + (size_t)B * DH / 2;

    if (ws_size < needed) {
        sentinel_kernel<<<2048, 256, 0, stream>>>(out, (long long)out_size);
        return;
    }

    char* ws = (char*)d_ws;
    unsigned* amax = (unsigned*)(ws + off_amax);  // [0]=x [1]=w1 [2]=h [3]=w2
    unsigned char* Xq = (unsigned char*)(ws + off_Xq);
    unsigned char* Wq = (unsigned char*)(ws + off_W);
    float*         h  = (float*)(ws + off_h);
    unsigned char* Hq = (unsigned char*)(ws + off_Hq);

    zero4_kernel<<<1, 64, 0, stream>>>(amax);

    // --- w1: absmax then immediate reversed re-read (L3-adjacent) ---
    absmax_kernel<<<2048, 256, 0, stream>>>(w1, (long long)DIN * DH, amax + 1);
    quant_transpose_pack_kernel<<<(DIN / 64) * (DH / 64), 256, 0, stream>>>(
        w1, DIN, DH, amax + 1, Wq);

    // --- x: absmax then immediate quant ---
    absmax_kernel<<<2048, 256, 0, stream>>>(x, (long long)B * DIN, amax + 0);
    quant_pack_rev_kernel<<<2048, 256, 0, stream>>>(x, (long long)B * DIN,
                                                    amax + 0, (unsigned*)Xq);

    // h = relu(Q(x) @ Q(w1) + b1), fused absmax(h) -> amax[2]  [tn-fast g1]
    gemm_fp4_g1<1, 1><<<(B / 128) * (DH / 128), 256, 0, stream>>>(
        Xq, Wq, h, b1, amax + 0, amax + 1, amax + 2, B, DH, DIN);

    // --- h: quant immediately after GEMM1, reversed, NT loads ---
    quant_pack_rev_kernel<<<2048, 256, 0, stream>>>(h, (long long)B * DH,
                                                    amax + 2, (unsigned*)Hq);

    // --- w2: absmax then immediate reversed re-read ---
    absmax_kernel<<<2048, 256, 0, stream>>>(w2, (long long)DH * DOUT, amax + 3);
    quant_transpose_pack_kernel<<<(DH / 64) * (DOUT / 64), 256, 0, stream>>>(
        w2, DH, DOUT, amax + 3, Wq);

    // out = Q(h) @ Q(w2) + b2   [256^2 pipeline]
    gemm_fp4_g2p<<<(B / 256) * (DOUT / 256), 512, 0, stream>>>(
        Hq, Wq, out, b2, amax + 2, amax + 3, B, DOUT, DH);
}

// Round 17
// 626.431 us; speedup vs baseline: 1.1376x; 1.0798x over previous
//
#include <hip/hip_runtime.h>
#include <hip/hip_bf16.h>

// FP4 fake-quant MLP via MX-FP4 MFMA (16x16x128, unit block scales).
// Round 17: single change vs r14-best (663.5us): g1 gets a CUTLASS-style
// GROUPED tile map (GM=8). r13 (tm-fast, FETCH 405MB) thrashed L2 with the
// 8MB A workset; r16 (tn-fast, FETCH 530MB) thrashed with the 16MB B workset.
// An 8tm x 8tn concurrent window = 2MB A + 2MB B = exactly 4MB L2 -> each
// panel fetched ~once. Schedule/epilogue byte-identical to the 197us champion.
// GEMM2 = r14 g2p (162us). Elementwise byte-identical to r14.

typedef float f32x4  __attribute__((ext_vector_type(4)));
typedef int   i32x4  __attribute__((ext_vector_type(4)));
typedef int   i32x8  __attribute__((ext_vector_type(8)));

#define AS1 __attribute__((address_space(1)))
#define AS3 __attribute__((address_space(3)))

#define SB0   __builtin_amdgcn_sched_barrier(0)
#define BAR   __builtin_amdgcn_s_barrier()
#define LGKM0 asm volatile("s_waitcnt lgkmcnt(0)" ::: "memory")

// ---------- quant helpers ----------
__device__ __forceinline__ float scale_from_amax_bits(unsigned bits) {
    return fmaxf(__uint_as_float(bits) / 6.0f, 1e-12f);
}

// FP4 e2m1 code: idx 0..7 over grid {0,.5,1,1.5,2,3,4,6}, sign in bit 3.
__device__ __forceinline__ unsigned q4(float v, float inv_scale) {
    float xs = fabsf(v) * inv_scale;
    unsigned idx = 0;
    idx += (xs > 0.25f);
    idx += (xs > 0.75f);
    idx += (xs > 1.25f);
    idx += (xs > 1.75f);
    idx += (xs > 2.5f);
    idx += (xs > 3.5f);
    idx += (xs > 5.0f);
    return idx | ((v < 0.0f) ? 8u : 0u);
}

// ---------- tiny utility kernels ----------
__global__ void zero4_kernel(unsigned* p) {
    if (threadIdx.x < 4) p[threadIdx.x] = 0u;
}

__global__ void sentinel_kernel(float* out, long long n) {
    long long i = (long long)blockIdx.x * blockDim.x + threadIdx.x;
    long long stride = (long long)gridDim.x * blockDim.x;
    for (; i < n; i += stride) out[i] = 1e30f;
}

// ---------- absmax reduction (n % 4 == 0) ----------
__global__ void absmax_kernel(const float* __restrict__ in, long long n,
                              unsigned* __restrict__ out) {
    long long i = ((long long)blockIdx.x * blockDim.x + threadIdx.x) * 4;
    long long stride = (long long)gridDim.x * blockDim.x * 4;
    float m = 0.0f;
    for (; i < n; i += stride) {
        f32x4 v = *(const f32x4*)&in[i];
        m = fmaxf(m, fmaxf(fmaxf(fabsf(v.x), fabsf(v.y)),
                           fmaxf(fabsf(v.z), fabsf(v.w))));
    }
    #pragma unroll
    for (int off = 32; off > 0; off >>= 1)
        m = fmaxf(m, __shfl_xor(m, off));
    __shared__ float smax[4];
    int lane = threadIdx.x & 63, w = threadIdx.x >> 6;
    if (lane == 0) smax[w] = m;
    __syncthreads();
    if (threadIdx.x == 0) {
        m = fmaxf(fmaxf(smax[0], smax[1]), fmaxf(smax[2], smax[3]));
        atomicMax(out, __float_as_uint(m));  // valid: all values >= 0
    }
}

// ---------- quantize f32 -> packed fp4, reversed, NT loads (last use) -------
__global__ void quant_pack_rev_kernel(const float* __restrict__ in, long long n,
                                      const unsigned* __restrict__ amax,
                                      unsigned* __restrict__ out) {
    float inv = 1.0f / scale_from_amax_bits(*amax);
    long long nw = n >> 3;
    long long gid = (long long)blockIdx.x * blockDim.x + threadIdx.x;
    long long gs = (long long)gridDim.x * blockDim.x;
    for (long long j = nw - 1 - gid; j >= 0; j -= gs) {
        long long i = j * 8;
        f32x4 a = __builtin_nontemporal_load((const f32x4*)&in[i]);
        f32x4 b = __builtin_nontemporal_load((const f32x4*)&in[i + 4]);
        unsigned u = q4(a.x, inv)        | (q4(a.y, inv) << 4)
                   | (q4(a.z, inv) << 8) | (q4(a.w, inv) << 12)
                   | (q4(b.x, inv) << 16)| (q4(b.y, inv) << 20)
                   | (q4(b.z, inv) << 24)| (q4(b.w, inv) << 28);
        out[j] = u;
    }
}

// ---------- quantize + transpose + pack, reversed tiles, NT loads ----------
__global__ void quant_transpose_pack_kernel(const float* __restrict__ in, int R, int C,
                                            const unsigned* __restrict__ amax,
                                            unsigned char* __restrict__ out) {
    __shared__ float tile[64][65];
    float inv = 1.0f / scale_from_amax_bits(*amax);
    int t = threadIdx.x;
    int bid = gridDim.x - 1 - blockIdx.x;   // reverse: L3-resident tail first
    int CT = C >> 6;
    int tc = bid % CT;
    int tr = bid / CT;
    int r0 = t >> 4;
    int c0 = (t & 15) * 4;
    #pragma unroll
    for (int it = 0; it < 4; ++it) {
        int r = r0 + it * 16;
        f32x4 v = __builtin_nontemporal_load(
            (const f32x4*)&in[(size_t)(tr * 64 + r) * C + tc * 64 + c0]);
        tile[r][c0 + 0] = v.x;
        tile[r][c0 + 1] = v.y;
        tile[r][c0 + 2] = v.z;
        tile[r][c0 + 3] = v.w;
    }
    __syncthreads();
    int c = t >> 2;
    int rch = (t & 3) * 16;
    unsigned u0 = 0, u1 = 0;
    #pragma unroll
    for (int j = 0; j < 8; ++j) u0 |= q4(tile[rch + j][c], inv) << (4 * j);
    #pragma unroll
    for (int j = 0; j < 8; ++j) u1 |= q4(tile[rch + 8 + j][c], inv) << (4 * j);
    uint2 o; o.x = u0; o.y = u1;
    *(uint2*)&out[(size_t)(tc * 64 + c) * (R >> 1) + (size_t)(tr * 32) + (rch >> 1)] = o;
}

// ---------- fp4 MFMA helper ----------
__device__ __forceinline__ f32x4 mm16(i32x4 a, i32x4 b, f32x4 c) {
    i32x8 a8 = {a[0], a[1], a[2], a[3], 0, 0, 0, 0};
    i32x8 b8 = {b[0], b[1], b[2], b[3], 0, 0, 0, 0};
    return __builtin_amdgcn_mfma_scale_f32_16x16x128_f8f6f4(
        a8, b8, c, 4, 4, 0, 0x7f7f7f7f, 0, 0x7f7f7f7f);
}

// ====== g1: r13 structure — 128x128 block, BK=256, single-buffer =============
// ONLY change vs the 197us champion: GROUPED tile map (GM=8) so each XCD's
// ~64 concurrent blocks span 8tm x 8tn -> A(2MB)+B(2MB) fits the 4MB L2.
template <int RELU, int FUSE_AMAX>
__global__ __launch_bounds__(256, 2)
void gemm_fp4_g1(const unsigned char* __restrict__ Ap,
                 const unsigned char* __restrict__ Bp,
                 float* __restrict__ C, const float* __restrict__ bias,
                 const unsigned* __restrict__ amaxA,
                 const unsigned* __restrict__ amaxB,
                 unsigned* __restrict__ amaxOut,
                 int M, int N, int K) {
    __shared__ alignas(16) unsigned char As[128 * 128];
    __shared__ alignas(16) unsigned char Bs[128 * 128];
    __shared__ float smax[4];

    int nwg = gridDim.x, cpx = nwg >> 3;
    int wg = (blockIdx.x & 7) * cpx + (blockIdx.x >> 3);
    // grouped map: GM=8 tm-rows per group; tm fastest within group, then tn.
    // bijective: MT (=M/128) divisible by 8 for M=4096.
    int NTl = N >> 7;
    int grp = wg / (8 * NTl);
    int rem = wg - grp * (8 * NTl);
    int tn = rem >> 3;
    int tm = grp * 8 + (rem & 7);

    int tid = threadIdx.x, lane = tid & 63, wid = tid >> 6;
    int wr = wid >> 1, wc = wid & 1;

    size_t Kb = (size_t)(K >> 1);

    int cs = ((lane & 7) ^ ((lane >> 3) & 7)) << 4;
    int srow = wid * 32 + (lane >> 3);
    const unsigned char* Abase = Ap + (size_t)(tm * 128 + srow) * Kb + cs;
    const unsigned char* Bbase = Bp + (size_t)(tn * 128 + srow) * Kb + cs;
    char* AsB = (char*)As;
    char* BsB = (char*)Bs;
    int ldsOff = wid * 4096;

    f32x4 acc[4][4] = {};
    int rrA = wr * 64 + (lane & 15);
    int rrB = wc * 64 + (lane & 15);

    int KT = K >> 8;
    for (int kt = 0; kt < KT; ++kt) {
        #pragma unroll
        for (int i = 0; i < 4; ++i) {
            __builtin_amdgcn_global_load_lds(
                (const AS1 void*)(Abase + (size_t)kt * 128 + (size_t)(i * 8) * Kb),
                (AS3 void*)(AsB + ldsOff + i * 1024), 16, 0, 0);
            __builtin_amdgcn_global_load_lds(
                (const AS1 void*)(Bbase + (size_t)kt * 128 + (size_t)(i * 8) * Kb),
                (AS3 void*)(BsB + ldsOff + i * 1024), 16, 0, 0);
        }
        __syncthreads();

        #pragma unroll
        for (int ks = 0; ks < 2; ++ks) {
            int slotOff = ((ks * 4 + (lane >> 4)) ^ (lane & 7)) << 4;
            i32x4 a[4], b[4];
            #pragma unroll
            for (int mi = 0; mi < 4; ++mi)
                a[mi] = *(const i32x4*)(AsB + (rrA + mi * 16) * 128 + slotOff);
            #pragma unroll
            for (int ni = 0; ni < 4; ++ni)
                b[ni] = *(const i32x4*)(BsB + (rrB + ni * 16) * 128 + slotOff);
            #pragma unroll
            for (int mi = 0; mi < 4; ++mi)
                #pragma unroll
                for (int ni = 0; ni < 4; ++ni)
                    acc[mi][ni] = mm16(a[mi], b[ni], acc[mi][ni]);
        }
        __syncthreads();
    }

    float s = scale_from_amax_bits(*amaxA) * scale_from_amax_bits(*amaxB);
    float vmax = 0.0f;
    int rowBase = tm * 128 + wr * 64 + (lane >> 4) * 4;
    int colBase = tn * 128 + wc * 64 + (lane & 15);
    #pragma unroll
    for (int mi = 0; mi < 4; ++mi) {
        #pragma unroll
        for (int ni = 0; ni < 4; ++ni) {
            int col = colBase + ni * 16;
            float bv = bias[col];
            int row = rowBase + mi * 16;
            #pragma unroll
            for (int r = 0; r < 4; ++r) {
                float v = acc[mi][ni][r] * s + bv;
                if (RELU) v = fmaxf(v, 0.0f);
                if (FUSE_AMAX) vmax = fmaxf(vmax, fabsf(v));
                __builtin_nontemporal_store(v, &C[(size_t)(row + r) * N + col]);
            }
        }
    }
    if (FUSE_AMAX) {
        #pragma unroll
        for (int off = 32; off > 0; off >>= 1)
            vmax = fmaxf(vmax, __shfl_xor(vmax, off));
        if (lane == 0) smax[wid] = vmax;
        __syncthreads();
        if (tid == 0) {
            vmax = fmaxf(fmaxf(smax[0], smax[1]), fmaxf(smax[2], smax[3]));
            atomicMax(amaxOut, __float_as_uint(vmax));
        }
    }
}

// ====== g2: 256x256 block, BK=128, 4-phase pipelined (r14 g2p, proven) ======
__global__ __launch_bounds__(512, 2)
void gemm_fp4_g2p(const unsigned char* __restrict__ Ap,
                  const unsigned char* __restrict__ Bp,
                  float* __restrict__ C, const float* __restrict__ bias,
                  const unsigned* __restrict__ amaxA,
                  const unsigned* __restrict__ amaxB,
                  int M, int N, int K) {
    __shared__ alignas(16) unsigned char As[2][256 * 64];  // 32 KB
    __shared__ alignas(16) unsigned char Bs[2][256 * 64];  // 32 KB

    int nwg = gridDim.x, cpx = nwg >> 3;
    int wg = (blockIdx.x & 7) * cpx + (blockIdx.x >> 3);
    int MT = M >> 8;
    int tm = wg % MT, tn = wg / MT;

    int tid = threadIdx.x, lane = tid & 63, wid = tid >> 6;  // wid 0..7
    int wr = wid >> 2;          // 0..1 : 128-row half
    int wc = wid & 3;           // 0..3 : 64-col quarter

    size_t Kb = (size_t)(K >> 1);

    int csw = ((tid & 3) ^ ((tid >> 3) & 3)) << 4;
    int srow = tid >> 2;
    const unsigned char* Abase = Ap + (size_t)(tm * 256 + srow) * Kb + csw;
    const unsigned char* Bbase = Bp + (size_t)(tn * 256 + srow) * Kb + csw;
    char* AsB = (char*)As;
    char* BsB = (char*)Bs;
    int dstOff = wid << 10;     // + lane*16 by HW

#define STG_A2(d, kt, h)                                                      \
    __builtin_amdgcn_global_load_lds(                                         \
        (const AS1 void*)(Abase + (size_t)(kt) * 64 + (size_t)((h) * 128) * Kb), \
        (AS3 void*)(AsB + ((d) << 14) + ((h) << 13) + dstOff), 16, 0, 0)
#define STG_B2(d, kt, h)                                                      \
    __builtin_amdgcn_global_load_lds(                                         \
        (const AS1 void*)(Bbase + (size_t)(kt) * 64 + (size_t)((h) * 128) * Kb), \
        (AS3 void*)(BsB + ((d) << 14) + ((h) << 13) + dstOff), 16, 0, 0)

    f32x4 acc[8][4] = {};
    int l15 = lane & 15;
    int rrA = wr * 128 + l15;   // + mi*16
    int rrB = wc * 64 + l15;    // + ni*16
    int slotOff = (((lane >> 4) ^ ((lane >> 1) & 3)) << 4);

    int KT = K >> 7;            // K-tiles of 128 fp4 (64B)

    // prologue: tile 0 -> buf0, tile 1 -> buf1; retire tile 0 (leave 4)
    STG_A2(0, 0, 0); STG_A2(0, 0, 1); STG_B2(0, 0, 0); STG_B2(0, 0, 1);
    STG_A2(1, 1, 0); STG_A2(1, 1, 1); STG_B2(1, 1, 0); STG_B2(1, 1, 1);
    asm volatile("s_waitcnt vmcnt(4)" ::: "memory");
    BAR;

    for (int t = 0; t < KT; ++t) {
        int d = t & 1;
        const char* Aq = AsB + (d << 14);
        const char* Bq = BsB + (d << 14);
        bool pf = (t + 2 < KT);
        i32x4 a0[4], a1[4], b[4];

        // ---- P1: read a[0..3] + b[0..3]; MFMA a0 x b01
        #pragma unroll
        for (int mi = 0; mi < 4; ++mi)
            a0[mi] = *(const i32x4*)(Aq + (rrA + mi * 16) * 64 + slotOff);
        #pragma unroll
        for (int ni = 0; ni < 4; ++ni)
            b[ni] = *(const i32x4*)(Bq + (rrB + ni * 16) * 64 + slotOff);
        SB0; BAR;
        LGKM0; SB0;
        __builtin_amdgcn_s_setprio(1);
        #pragma unroll
        for (int mi = 0; mi < 4; ++mi)
            #pragma unroll
            for (int ni = 0; ni < 2; ++ni)
                acc[mi][ni] = mm16(a0[mi], b[ni], acc[mi][ni]);
        __builtin_amdgcn_s_setprio(0);
        SB0; BAR;

        // ---- P2: read a[4..7]; stage B(t+2) into buf d (B reads retired P1)
        #pragma unroll
        for (int mi = 0; mi < 4; ++mi)
            a1[mi] = *(const i32x4*)(Aq + (rrA + (4 + mi) * 16) * 64 + slotOff);
        if (pf) { STG_B2(d, t + 2, 0); STG_B2(d, t + 2, 1); }
        SB0; BAR;
        __builtin_amdgcn_s_setprio(1);
        #pragma unroll
        for (int mi = 0; mi < 4; ++mi)
            #pragma unroll
            for (int ni = 2; ni < 4; ++ni)
                acc[mi][ni] = mm16(a0[mi], b[ni], acc[mi][ni]);
        __builtin_amdgcn_s_setprio(0);
        SB0;
        LGKM0;              // a1 retired before P2-end barrier
        BAR;

        // ---- P3: stage A(t+2) into buf d (A reads retired above); MFMA
        if (pf) { STG_A2(d, t + 2, 0); STG_A2(d, t + 2, 1); }
        SB0; BAR;
        __builtin_amdgcn_s_setprio(1);
        #pragma unroll
        for (int mi = 0; mi < 4; ++mi)
            #pragma unroll
            for (int ni = 0; ni < 2; ++ni)
                acc[4 + mi][ni] = mm16(a1[mi], b[ni], acc[4 + mi][ni]);
        __builtin_amdgcn_s_setprio(0);
        SB0; BAR;

        // ---- P4: MFMA; counted vmcnt gate (retire tile t+1's 4 loads)
        __builtin_amdgcn_s_setprio(1);
        #pragma unroll
        for (int mi = 0; mi < 4; ++mi)
            #pragma unroll
            for (int ni = 2; ni < 4; ++ni)
                acc[4 + mi][ni] = mm16(a1[mi], b[ni], acc[4 + mi][ni]);
        __builtin_amdgcn_s_setprio(0);
        SB0;
        if (pf) { asm volatile("s_waitcnt vmcnt(4)" ::: "memory"); }
        else    { asm volatile("s_waitcnt vmcnt(0)" ::: "memory"); }
        BAR;
    }
#undef STG_A2
#undef STG_B2

    float s = scale_from_amax_bits(*amaxA) * scale_from_amax_bits(*amaxB);
    int rowBase = tm * 256 + wr * 128 + (lane >> 4) * 4;
    int colBase = tn * 256 + wc * 64 + l15;
    #pragma unroll
    for (int mi = 0; mi < 8; ++mi) {
        #pragma unroll
        for (int ni = 0; ni < 4; ++ni) {
            int col = colBase + ni * 16;
            float bv = bias[col];
            int row = rowBase + mi * 16;
            #pragma unroll
            for (int r = 0; r < 4; ++r) {
                float v = acc[mi][ni][r] * s + bv;
                __builtin_nontemporal_store(v, &C[(size_t)(row + r) * N + col]);
            }
        }
    }
}

// ---------- launch ----------
extern "C" void kernel_launch(void* const* d_in, const int* in_sizes, int n_in,
                              void* d_out, int out_size, void* d_ws, size_t ws_size,
                              hipStream_t stream) {
    const float* x  = (const float*)d_in[0];
    const float* w1 = (const float*)d_in[1];
    const float* b1 = (const float*)d_in[2];
    const float* w2 = (const float*)d_in[3];
    const float* b2 = (const float*)d_in[4];
    float* out = (float*)d_out;

    const int B = 4096, DIN = 4096, DH = 16384, DOUT = 4096;

    const size_t off_amax = 0;                                    // 4 uints
    const size_t off_Xq   = 256;                                  // 8 MB
    const size_t off_W    = off_Xq + (size_t)B * DIN / 2;         // 32 MB
    const size_t off_h    = off_W + (size_t)DIN * DH / 2;         // 256 MB f32
    const size_t off_Hq   = off_h + (size_t)B * DH * 4;           // 32 MB
    const size_t needed   = off_Hq + (size_t)B * DH / 2;

    if (ws_size < needed) {
        sentinel_kernel<<<2048, 256, 0, stream>>>(out, (long long)out_size);
        return;
    }

    char* ws = (char*)d_ws;
    unsigned* amax = (unsigned*)(ws + off_amax);  // [0]=x [1]=w1 [2]=h [3]=w2
    unsigned char* Xq = (unsigned char*)(ws + off_Xq);
    unsigned char* Wq = (unsigned char*)(ws + off_W);
    float*         h  = (float*)(ws + off_h);
    unsigned char* Hq = (unsigned char*)(ws + off_Hq);

    zero4_kernel<<<1, 64, 0, stream>>>(amax);

    // --- w1: absmax then immediate reversed re-read (L3-adjacent) ---
    absmax_kernel<<<2048, 256, 0, stream>>>(w1, (long long)DIN * DH, amax + 1);
    quant_transpose_pack_kernel<<<(DIN / 64) * (DH / 64), 256, 0, stream>>>(
        w1, DIN, DH, amax + 1, Wq);

    // --- x: absmax then immediate quant ---
    absmax_kernel<<<2048, 256, 0, stream>>>(x, (long long)B * DIN, amax + 0);
    quant_pack_rev_kernel<<<2048, 256, 0, stream>>>(x, (long long)B * DIN,
                                                    amax + 0, (unsigned*)Xq);

    // h = relu(Q(x) @ Q(w1) + b1), fused absmax(h) -> amax[2]  [grouped g1]
    gemm_fp4_g1<1, 1><<<(B / 128) * (DH / 128), 256, 0, stream>>>(
        Xq, Wq, h, b1, amax + 0, amax + 1, amax + 2, B, DH, DIN);

    // --- h: quant immediately after GEMM1, reversed, NT loads ---
    quant_pack_rev_kernel<<<2048, 256, 0, stream>>>(h, (long long)B * DH,
                                                    amax + 2, (unsigned*)Hq);

    // --- w2: absmax then immediate reversed re-read ---
    absmax_kernel<<<2048, 256, 0, stream>>>(w2, (long long)DH * DOUT, amax + 3);
    quant_transpose_pack_kernel<<<(DH / 64) * (DOUT / 64), 256, 0, stream>>>(
        w2, DH, DOUT, amax + 3, Wq);

    // out = Q(h) @ Q(w2) + b2   [256^2 pipeline]
    gemm_fp4_g2p<<<(B / 256) * (DOUT / 256), 512, 0, stream>>>(
        Hq, Wq, out, b2, amax + 2, amax + 3, B, DOUT, DH);
}

// Round 18
// 622.914 us; speedup vs baseline: 1.1440x; 1.0056x over previous
//
#include <hip/hip_runtime.h>
#include <hip/hip_bf16.h>

// FP4 fake-quant MLP via MX-FP4 MFMA (16x16x128, unit block scales).
// Round 18, two independent single-variable arms vs the 626us champion:
//  Arm1 (g1): h-store NT -> NORMAL. GM=8 now protects operands at L2, so the
//    h stream can be L3-retained; quant_pack(h) (reversed) then reads h from
//    L3 instead of HBM (~50us -> ~25us). Watch g1 FETCH for L2 re-pollution.
//  Arm2 (g2p): GM=8 grouped tile map (index-only; 36MB -> 24MB per-XCD
//    window for L3-ordering).
// Everything else byte-identical to r17.

typedef float f32x4  __attribute__((ext_vector_type(4)));
typedef int   i32x4  __attribute__((ext_vector_type(4)));
typedef int   i32x8  __attribute__((ext_vector_type(8)));

#define AS1 __attribute__((address_space(1)))
#define AS3 __attribute__((address_space(3)))

#define SB0   __builtin_amdgcn_sched_barrier(0)
#define BAR   __builtin_amdgcn_s_barrier()
#define LGKM0 asm volatile("s_waitcnt lgkmcnt(0)" ::: "memory")

// ---------- quant helpers ----------
__device__ __forceinline__ float scale_from_amax_bits(unsigned bits) {
    return fmaxf(__uint_as_float(bits) / 6.0f, 1e-12f);
}

// FP4 e2m1 code: idx 0..7 over grid {0,.5,1,1.5,2,3,4,6}, sign in bit 3.
__device__ __forceinline__ unsigned q4(float v, float inv_scale) {
    float xs = fabsf(v) * inv_scale;
    unsigned idx = 0;
    idx += (xs > 0.25f);
    idx += (xs > 0.75f);
    idx += (xs > 1.25f);
    idx += (xs > 1.75f);
    idx += (xs > 2.5f);
    idx += (xs > 3.5f);
    idx += (xs > 5.0f);
    return idx | ((v < 0.0f) ? 8u : 0u);
}

// ---------- tiny utility kernels ----------
__global__ void zero4_kernel(unsigned* p) {
    if (threadIdx.x < 4) p[threadIdx.x] = 0u;
}

__global__ void sentinel_kernel(float* out, long long n) {
    long long i = (long long)blockIdx.x * blockDim.x + threadIdx.x;
    long long stride = (long long)gridDim.x * blockDim.x;
    for (; i < n; i += stride) out[i] = 1e30f;
}

// ---------- absmax reduction (n % 4 == 0) ----------
__global__ void absmax_kernel(const float* __restrict__ in, long long n,
                              unsigned* __restrict__ out) {
    long long i = ((long long)blockIdx.x * blockDim.x + threadIdx.x) * 4;
    long long stride = (long long)gridDim.x * blockDim.x * 4;
    float m = 0.0f;
    for (; i < n; i += stride) {
        f32x4 v = *(const f32x4*)&in[i];
        m = fmaxf(m, fmaxf(fmaxf(fabsf(v.x), fabsf(v.y)),
                           fmaxf(fabsf(v.z), fabsf(v.w))));
    }
    #pragma unroll
    for (int off = 32; off > 0; off >>= 1)
        m = fmaxf(m, __shfl_xor(m, off));
    __shared__ float smax[4];
    int lane = threadIdx.x & 63, w = threadIdx.x >> 6;
    if (lane == 0) smax[w] = m;
    __syncthreads();
    if (threadIdx.x == 0) {
        m = fmaxf(fmaxf(smax[0], smax[1]), fmaxf(smax[2], smax[3]));
        atomicMax(out, __float_as_uint(m));  // valid: all values >= 0
    }
}

// ---------- quantize f32 -> packed fp4, reversed, NT loads (last use) -------
__global__ void quant_pack_rev_kernel(const float* __restrict__ in, long long n,
                                      const unsigned* __restrict__ amax,
                                      unsigned* __restrict__ out) {
    float inv = 1.0f / scale_from_amax_bits(*amax);
    long long nw = n >> 3;
    long long gid = (long long)blockIdx.x * blockDim.x + threadIdx.x;
    long long gs = (long long)gridDim.x * blockDim.x;
    for (long long j = nw - 1 - gid; j >= 0; j -= gs) {
        long long i = j * 8;
        f32x4 a = __builtin_nontemporal_load((const f32x4*)&in[i]);
        f32x4 b = __builtin_nontemporal_load((const f32x4*)&in[i + 4]);
        unsigned u = q4(a.x, inv)        | (q4(a.y, inv) << 4)
                   | (q4(a.z, inv) << 8) | (q4(a.w, inv) << 12)
                   | (q4(b.x, inv) << 16)| (q4(b.y, inv) << 20)
                   | (q4(b.z, inv) << 24)| (q4(b.w, inv) << 28);
        out[j] = u;
    }
}

// ---------- quantize + transpose + pack, reversed tiles, NT loads ----------
__global__ void quant_transpose_pack_kernel(const float* __restrict__ in, int R, int C,
                                            const unsigned* __restrict__ amax,
                                            unsigned char* __restrict__ out) {
    __shared__ float tile[64][65];
    float inv = 1.0f / scale_from_amax_bits(*amax);
    int t = threadIdx.x;
    int bid = gridDim.x - 1 - blockIdx.x;   // reverse: L3-resident tail first
    int CT = C >> 6;
    int tc = bid % CT;
    int tr = bid / CT;
    int r0 = t >> 4;
    int c0 = (t & 15) * 4;
    #pragma unroll
    for (int it = 0; it < 4; ++it) {
        int r = r0 + it * 16;
        f32x4 v = __builtin_nontemporal_load(
            (const f32x4*)&in[(size_t)(tr * 64 + r) * C + tc * 64 + c0]);
        tile[r][c0 + 0] = v.x;
        tile[r][c0 + 1] = v.y;
        tile[r][c0 + 2] = v.z;
        tile[r][c0 + 3] = v.w;
    }
    __syncthreads();
    int c = t >> 2;
    int rch = (t & 3) * 16;
    unsigned u0 = 0, u1 = 0;
    #pragma unroll
    for (int j = 0; j < 8; ++j) u0 |= q4(tile[rch + j][c], inv) << (4 * j);
    #pragma unroll
    for (int j = 0; j < 8; ++j) u1 |= q4(tile[rch + 8 + j][c], inv) << (4 * j);
    uint2 o; o.x = u0; o.y = u1;
    *(uint2*)&out[(size_t)(tc * 64 + c) * (R >> 1) + (size_t)(tr * 32) + (rch >> 1)] = o;
}

// ---------- fp4 MFMA helper ----------
__device__ __forceinline__ f32x4 mm16(i32x4 a, i32x4 b, f32x4 c) {
    i32x8 a8 = {a[0], a[1], a[2], a[3], 0, 0, 0, 0};
    i32x8 b8 = {b[0], b[1], b[2], b[3], 0, 0, 0, 0};
    return __builtin_amdgcn_mfma_scale_f32_16x16x128_f8f6f4(
        a8, b8, c, 4, 4, 0, 0x7f7f7f7f, 0, 0x7f7f7f7f);
}

// ====== g1: 128x128 block, BK=256, single-buffer, GM=8 grouped map ==========
// Arm1 change: C (h) stored with NORMAL stores (L3-retained for quant pass).
template <int RELU, int FUSE_AMAX>
__global__ __launch_bounds__(256, 2)
void gemm_fp4_g1(const unsigned char* __restrict__ Ap,
                 const unsigned char* __restrict__ Bp,
                 float* __restrict__ C, const float* __restrict__ bias,
                 const unsigned* __restrict__ amaxA,
                 const unsigned* __restrict__ amaxB,
                 unsigned* __restrict__ amaxOut,
                 int M, int N, int K) {
    __shared__ alignas(16) unsigned char As[128 * 128];
    __shared__ alignas(16) unsigned char Bs[128 * 128];
    __shared__ float smax[4];

    int nwg = gridDim.x, cpx = nwg >> 3;
    int wg = (blockIdx.x & 7) * cpx + (blockIdx.x >> 3);
    int NTl = N >> 7;
    int grp = wg / (8 * NTl);
    int rem = wg - grp * (8 * NTl);
    int tn = rem >> 3;
    int tm = grp * 8 + (rem & 7);

    int tid = threadIdx.x, lane = tid & 63, wid = tid >> 6;
    int wr = wid >> 1, wc = wid & 1;

    size_t Kb = (size_t)(K >> 1);

    int cs = ((lane & 7) ^ ((lane >> 3) & 7)) << 4;
    int srow = wid * 32 + (lane >> 3);
    const unsigned char* Abase = Ap + (size_t)(tm * 128 + srow) * Kb + cs;
    const unsigned char* Bbase = Bp + (size_t)(tn * 128 + srow) * Kb + cs;
    char* AsB = (char*)As;
    char* BsB = (char*)Bs;
    int ldsOff = wid * 4096;

    f32x4 acc[4][4] = {};
    int rrA = wr * 64 + (lane & 15);
    int rrB = wc * 64 + (lane & 15);

    int KT = K >> 8;
    for (int kt = 0; kt < KT; ++kt) {
        #pragma unroll
        for (int i = 0; i < 4; ++i) {
            __builtin_amdgcn_global_load_lds(
                (const AS1 void*)(Abase + (size_t)kt * 128 + (size_t)(i * 8) * Kb),
                (AS3 void*)(AsB + ldsOff + i * 1024), 16, 0, 0);
            __builtin_amdgcn_global_load_lds(
                (const AS1 void*)(Bbase + (size_t)kt * 128 + (size_t)(i * 8) * Kb),
                (AS3 void*)(BsB + ldsOff + i * 1024), 16, 0, 0);
        }
        __syncthreads();

        #pragma unroll
        for (int ks = 0; ks < 2; ++ks) {
            int slotOff = ((ks * 4 + (lane >> 4)) ^ (lane & 7)) << 4;
            i32x4 a[4], b[4];
            #pragma unroll
            for (int mi = 0; mi < 4; ++mi)
                a[mi] = *(const i32x4*)(AsB + (rrA + mi * 16) * 128 + slotOff);
            #pragma unroll
            for (int ni = 0; ni < 4; ++ni)
                b[ni] = *(const i32x4*)(BsB + (rrB + ni * 16) * 128 + slotOff);
            #pragma unroll
            for (int mi = 0; mi < 4; ++mi)
                #pragma unroll
                for (int ni = 0; ni < 4; ++ni)
                    acc[mi][ni] = mm16(a[mi], b[ni], acc[mi][ni]);
        }
        __syncthreads();
    }

    float s = scale_from_amax_bits(*amaxA) * scale_from_amax_bits(*amaxB);
    float vmax = 0.0f;
    int rowBase = tm * 128 + wr * 64 + (lane >> 4) * 4;
    int colBase = tn * 128 + wc * 64 + (lane & 15);
    #pragma unroll
    for (int mi = 0; mi < 4; ++mi) {
        #pragma unroll
        for (int ni = 0; ni < 4; ++ni) {
            int col = colBase + ni * 16;
            float bv = bias[col];
            int row = rowBase + mi * 16;
            #pragma unroll
            for (int r = 0; r < 4; ++r) {
                float v = acc[mi][ni][r] * s + bv;
                if (RELU) v = fmaxf(v, 0.0f);
                if (FUSE_AMAX) vmax = fmaxf(vmax, fabsf(v));
                C[(size_t)(row + r) * N + col] = v;   // NORMAL store (arm 1)
            }
        }
    }
    if (FUSE_AMAX) {
        #pragma unroll
        for (int off = 32; off > 0; off >>= 1)
            vmax = fmaxf(vmax, __shfl_xor(vmax, off));
        if (lane == 0) smax[wid] = vmax;
        __syncthreads();
        if (tid == 0) {
            vmax = fmaxf(fmaxf(smax[0], smax[1]), fmaxf(smax[2], smax[3]));
            atomicMax(amaxOut, __float_as_uint(vmax));
        }
    }
}

// ====== g2: 256x256 block, BK=128, 4-phase pipelined + GM=8 grouped map =====
__global__ __launch_bounds__(512, 2)
void gemm_fp4_g2p(const unsigned char* __restrict__ Ap,
                  const unsigned char* __restrict__ Bp,
                  float* __restrict__ C, const float* __restrict__ bias,
                  const unsigned* __restrict__ amaxA,
                  const unsigned* __restrict__ amaxB,
                  int M, int N, int K) {
    __shared__ alignas(16) unsigned char As[2][256 * 64];  // 32 KB
    __shared__ alignas(16) unsigned char Bs[2][256 * 64];  // 32 KB

    int nwg = gridDim.x, cpx = nwg >> 3;
    int wg = (blockIdx.x & 7) * cpx + (blockIdx.x >> 3);
    // Arm2: grouped map GM=8 (8 tm-rows per group, tm fastest).
    int NTl = N >> 8;
    int grp = wg / (8 * NTl);
    int rem = wg - grp * (8 * NTl);
    int tn = rem >> 3;
    int tm = grp * 8 + (rem & 7);

    int tid = threadIdx.x, lane = tid & 63, wid = tid >> 6;  // wid 0..7
    int wr = wid >> 2;          // 0..1 : 128-row half
    int wc = wid & 3;           // 0..3 : 64-col quarter

    size_t Kb = (size_t)(K >> 1);

    int csw = ((tid & 3) ^ ((tid >> 3) & 3)) << 4;
    int srow = tid >> 2;
    const unsigned char* Abase = Ap + (size_t)(tm * 256 + srow) * Kb + csw;
    const unsigned char* Bbase = Bp + (size_t)(tn * 256 + srow) * Kb + csw;
    char* AsB = (char*)As;
    char* BsB = (char*)Bs;
    int dstOff = wid << 10;     // + lane*16 by HW

#define STG_A2(d, kt, h)                                                      \
    __builtin_amdgcn_global_load_lds(                                         \
        (const AS1 void*)(Abase + (size_t)(kt) * 64 + (size_t)((h) * 128) * Kb), \
        (AS3 void*)(AsB + ((d) << 14) + ((h) << 13) + dstOff), 16, 0, 0)
#define STG_B2(d, kt, h)                                                      \
    __builtin_amdgcn_global_load_lds(                                         \
        (const AS1 void*)(Bbase + (size_t)(kt) * 64 + (size_t)((h) * 128) * Kb), \
        (AS3 void*)(BsB + ((d) << 14) + ((h) << 13) + dstOff), 16, 0, 0)

    f32x4 acc[8][4] = {};
    int l15 = lane & 15;
    int rrA = wr * 128 + l15;   // + mi*16
    int rrB = wc * 64 + l15;    // + ni*16
    int slotOff = (((lane >> 4) ^ ((lane >> 1) & 3)) << 4);

    int KT = K >> 7;            // K-tiles of 128 fp4 (64B)

    // prologue: tile 0 -> buf0, tile 1 -> buf1; retire tile 0 (leave 4)
    STG_A2(0, 0, 0); STG_A2(0, 0, 1); STG_B2(0, 0, 0); STG_B2(0, 0, 1);
    STG_A2(1, 1, 0); STG_A2(1, 1, 1); STG_B2(1, 1, 0); STG_B2(1, 1, 1);
    asm volatile("s_waitcnt vmcnt(4)" ::: "memory");
    BAR;

    for (int t = 0; t < KT; ++t) {
        int d = t & 1;
        const char* Aq = AsB + (d << 14);
        const char* Bq = BsB + (d << 14);
        bool pf = (t + 2 < KT);
        i32x4 a0[4], a1[4], b[4];

        // ---- P1: read a[0..3] + b[0..3]; MFMA a0 x b01
        #pragma unroll
        for (int mi = 0; mi < 4; ++mi)
            a0[mi] = *(const i32x4*)(Aq + (rrA + mi * 16) * 64 + slotOff);
        #pragma unroll
        for (int ni = 0; ni < 4; ++ni)
            b[ni] = *(const i32x4*)(Bq + (rrB + ni * 16) * 64 + slotOff);
        SB0; BAR;
        LGKM0; SB0;
        __builtin_amdgcn_s_setprio(1);
        #pragma unroll
        for (int mi = 0; mi < 4; ++mi)
            #pragma unroll
            for (int ni = 0; ni < 2; ++ni)
                acc[mi][ni] = mm16(a0[mi], b[ni], acc[mi][ni]);
        __builtin_amdgcn_s_setprio(0);
        SB0; BAR;

        // ---- P2: read a[4..7]; stage B(t+2) into buf d (B reads retired P1)
        #pragma unroll
        for (int mi = 0; mi < 4; ++mi)
            a1[mi] = *(const i32x4*)(Aq + (rrA + (4 + mi) * 16) * 64 + slotOff);
        if (pf) { STG_B2(d, t + 2, 0); STG_B2(d, t + 2, 1); }
        SB0; BAR;
        __builtin_amdgcn_s_setprio(1);
        #pragma unroll
        for (int mi = 0; mi < 4; ++mi)
            #pragma unroll
            for (int ni = 2; ni < 4; ++ni)
                acc[mi][ni] = mm16(a0[mi], b[ni], acc[mi][ni]);
        __builtin_amdgcn_s_setprio(0);
        SB0;
        LGKM0;              // a1 retired before P2-end barrier
        BAR;

        // ---- P3: stage A(t+2) into buf d (A reads retired above); MFMA
        if (pf) { STG_A2(d, t + 2, 0); STG_A2(d, t + 2, 1); }
        SB0; BAR;
        __builtin_amdgcn_s_setprio(1);
        #pragma unroll
        for (int mi = 0; mi < 4; ++mi)
            #pragma unroll
            for (int ni = 0; ni < 2; ++ni)
                acc[4 + mi][ni] = mm16(a1[mi], b[ni], acc[4 + mi][ni]);
        __builtin_amdgcn_s_setprio(0);
        SB0; BAR;

        // ---- P4: MFMA; counted vmcnt gate (retire tile t+1's 4 loads)
        __builtin_amdgcn_s_setprio(1);
        #pragma unroll
        for (int mi = 0; mi < 4; ++mi)
            #pragma unroll
            for (int ni = 2; ni < 4; ++ni)
                acc[4 + mi][ni] = mm16(a1[mi], b[ni], acc[4 + mi][ni]);
        __builtin_amdgcn_s_setprio(0);
        SB0;
        if (pf) { asm volatile("s_waitcnt vmcnt(4)" ::: "memory"); }
        else    { asm volatile("s_waitcnt vmcnt(0)" ::: "memory"); }
        BAR;
    }
#undef STG_A2
#undef STG_B2

    float s = scale_from_amax_bits(*amaxA) * scale_from_amax_bits(*amaxB);
    int rowBase = tm * 256 + wr * 128 + (lane >> 4) * 4;
    int colBase = tn * 256 + wc * 64 + l15;
    #pragma unroll
    for (int mi = 0; mi < 8; ++mi) {
        #pragma unroll
        for (int ni = 0; ni < 4; ++ni) {
            int col = colBase + ni * 16;
            float bv = bias[col];
            int row = rowBase + mi * 16;
            #pragma unroll
            for (int r = 0; r < 4; ++r) {
                float v = acc[mi][ni][r] * s + bv;
                __builtin_nontemporal_store(v, &C[(size_t)(row + r) * N + col]);
            }
        }
    }
}

// ---------- launch ----------
extern "C" void kernel_launch(void* const* d_in, const int* in_sizes, int n_in,
                              void* d_out, int out_size, void* d_ws, size_t ws_size,
                              hipStream_t stream) {
    const float* x  = (const float*)d_in[0];
    const float* w1 = (const float*)d_in[1];
    const float* b1 = (const float*)d_in[2];
    const float* w2 = (const float*)d_in[3];
    const float* b2 = (const float*)d_in[4];
    float* out = (float*)d_out;

    const int B = 4096, DIN = 4096, DH = 16384, DOUT = 4096;

    const size_t off_amax = 0;                                    // 4 uints
    const size_t off_Xq   = 256;                                  // 8 MB
    const size_t off_W    = off_Xq + (size_t)B * DIN / 2;         // 32 MB
    const size_t off_h    = off_W + (size_t)DIN * DH / 2;         // 256 MB f32
    const size_t off_Hq   = off_h + (size_t)B * DH * 4;           // 32 MB
    const size_t needed   = off_Hq + (size_t)B * DH / 2;

    if (ws_size < needed) {
        sentinel_kernel<<<2048, 256, 0, stream>>>(out, (long long)out_size);
        return;
    }

    char* ws = (char*)d_ws;
    unsigned* amax = (unsigned*)(ws + off_amax);  // [0]=x [1]=w1 [2]=h [3]=w2
    unsigned char* Xq = (unsigned char*)(ws + off_Xq);
    unsigned char* Wq = (unsigned char*)(ws + off_W);
    float*         h  = (float*)(ws + off_h);
    unsigned char* Hq = (unsigned char*)(ws + off_Hq);

    zero4_kernel<<<1, 64, 0, stream>>>(amax);

    // --- w1: absmax then immediate reversed re-read (L3-adjacent) ---
    absmax_kernel<<<2048, 256, 0, stream>>>(w1, (long long)DIN * DH, amax + 1);
    quant_transpose_pack_kernel<<<(DIN / 64) * (DH / 64), 256, 0, stream>>>(
        w1, DIN, DH, amax + 1, Wq);

    // --- x: absmax then immediate quant ---
    absmax_kernel<<<2048, 256, 0, stream>>>(x, (long long)B * DIN, amax + 0);
    quant_pack_rev_kernel<<<2048, 256, 0, stream>>>(x, (long long)B * DIN,
                                                    amax + 0, (unsigned*)Xq);

    // h = relu(Q(x) @ Q(w1) + b1), fused absmax(h) -> amax[2]
    gemm_fp4_g1<1, 1><<<(B / 128) * (DH / 128), 256, 0, stream>>>(
        Xq, Wq, h, b1, amax + 0, amax + 1, amax + 2, B, DH, DIN);

    // --- h: quant immediately after GEMM1, reversed, NT loads ---
    quant_pack_rev_kernel<<<2048, 256, 0, stream>>>(h, (long long)B * DH,
                                                    amax + 2, (unsigned*)Hq);

    // --- w2: absmax then immediate reversed re-read ---
    absmax_kernel<<<2048, 256, 0, stream>>>(w2, (long long)DH * DOUT, amax + 3);
    quant_transpose_pack_kernel<<<(DH / 64) * (DOUT / 64), 256, 0, stream>>>(
        w2, DH, DOUT, amax + 3, Wq);

    // out = Q(h) @ Q(w2) + b2   [256^2 pipeline + grouped map]
    gemm_fp4_g2p<<<(B / 256) * (DOUT / 256), 512, 0, stream>>>(
        Hq, Wq, out, b2, amax + 2, amax + 3, B, DOUT, DH);
}